// Round 14
// baseline (171.459 us; speedup 1.0000x reference)
//
#include <hip/hip_runtime.h>
#include <hip/hip_bf16.h>
#include <math.h>

#define N_NODES 50000
#define N_EDGES 800000
#define DIM 64
#define RW 196            // nodes per range
#define NR 256            // ranges: 256*196 = 50176 >= 50000
#define SEGCAP 4096       // per-range segment capacity (mean 3136, +17 sigma)
#define NB1 196           // pass-1 blocks
#define EPB1 4096         // edges per pass-1 block (196*4096 = 802816 >= 800000)
#define CPAD 16           // segment-cursor padding (ints) -> one counter per 64B line

// ---------- helpers ----------
__device__ __forceinline__ float wave_reduce_sum(float x) {
#pragma unroll
  for (int off = 32; off > 0; off >>= 1) x += __shfl_xor(x, off, 64);
  return x;
}

__device__ __forceinline__ unsigned int f2bf_bits(float x) {  // fp32 -> bf16 bits, RNE
  unsigned int u = __float_as_uint(x);
  return (u + 0x7fffu + ((u >> 16) & 1u)) >> 16;
}

// ---------- kernel 1: coarse partition — bin edges by dst/RW into range segments ----------
// 196 blocks x 256; 4096 edges/block staged in LDS; 50k global atomics total (was 800k)
__global__ __launch_bounds__(256) void k_part1(
    const int* __restrict__ src, const int* __restrict__ dst,
    int* __restrict__ segcur, int2* __restrict__ pairs)
{
  __shared__ int2 pr[EPB1];                       // 32 KB (d, s)
  __shared__ int cnt[NR], gb[NR], lcur[NR];
  const int t = threadIdx.x;
  cnt[t] = 0; lcur[t] = 0;
  __syncthreads();
#pragma unroll
  for (int k = 0; k < EPB1 / 256; ++k) {
    const int i = blockIdx.x * EPB1 + k * 256 + t;
    int d = -1, s = 0;
    if (i < N_EDGES) { d = dst[i]; s = src[i]; atomicAdd(&cnt[(unsigned)d / RW], 1); }
    pr[k * 256 + t] = make_int2(d, s);
  }
  __syncthreads();
  gb[t] = atomicAdd(&segcur[t * CPAD], cnt[t]);   // one global atomic per (block,bin)
  __syncthreads();
#pragma unroll
  for (int k = 0; k < EPB1 / 256; ++k) {
    const int2 p = pr[k * 256 + t];
    if (p.x >= 0) {
      const int bin = (unsigned)p.x / RW;
      const int l = gb[bin] + atomicAdd(&lcur[bin], 1);
      if (l < SEGCAP) pairs[bin * SEGCAP + l] = p; // 8B store, ~8/line within block window -> L2 merges
    }
  }
}

// ---------- kernel 2: node projections (scatter removed) ----------
// 3125 blocks x 256: 16 nodes/block (3125*16 = 50000)
__global__ __launch_bounds__(256) void k_proj(
    const float* __restrict__ v, const float* __restrict__ Wa,
    const float* __restrict__ att_l, const float* __restrict__ att_r,
    const float* __restrict__ gate_l, const float* __restrict__ gate_r,
    const float* __restrict__ Wgm,
    unsigned int* __restrict__ zg, float2* __restrict__ elgr,
    float* __restrict__ erv, float* __restrict__ glv)
{
  const int t = threadIdx.x;
  __shared__ float4 vL[16 * 16];
  const int nb = blockIdx.x * 16;
  vL[t] = ((const float4*)v)[nb * 16 + t];
  __syncthreads();

  const int wave = t >> 6, lane = t & 63;
  const float glw = gate_l[lane], grw = gate_r[lane];

#pragma unroll
  for (int it = 0; it < 4; ++it) {
    const int nl = wave * 4 + it;
    const float vj = ((const float*)vL)[nl * 64 + lane];
    const float gl_ = wave_reduce_sum(vj * glw);
    const float gr_ = wave_reduce_sum(vj * grw);
    if (lane == 0) { glv[nb + nl] = gl_; elgr[nb + nl].y = gr_; }
  }

  float wa[DIM], wg[DIM];
#pragma unroll
  for (int k = 0; k < DIM; ++k) {
    wa[k] = Wa[k * DIM + lane];
    wg[k] = Wgm[k * DIM + lane];
  }
  const float al = att_l[lane], ar = att_r[lane];

#pragma unroll
  for (int it = 0; it < 4; ++it) {
    const int nl = wave * 4 + it;
    const int n = nb + nl;
    float z0 = 0.f, z1 = 0.f, g0 = 0.f, g1 = 0.f;
#pragma unroll
    for (int j = 0; j < 16; ++j) {
      const float4 vv = vL[nl * 16 + j];        // LDS broadcast (same addr all lanes)
      z0 = fmaf(vv.x, wa[4 * j + 0], z0);
      g0 = fmaf(vv.x, wg[4 * j + 0], g0);
      z1 = fmaf(vv.y, wa[4 * j + 1], z1);
      g1 = fmaf(vv.y, wg[4 * j + 1], g1);
      z0 = fmaf(vv.z, wa[4 * j + 2], z0);
      g0 = fmaf(vv.z, wg[4 * j + 2], g0);
      z1 = fmaf(vv.w, wa[4 * j + 3], z1);
      g1 = fmaf(vv.w, wg[4 * j + 3], g1);
    }
    const float zj = z0 + z1, gj = g0 + g1;
    const float el_ = wave_reduce_sum(zj * al);
    const float er_ = wave_reduce_sum(zj * ar);
    zg[n * DIM + lane] = (f2bf_bits(zj) << 16) | f2bf_bits(gj);  // z hi, gproj lo
    if (lane == 0) { elgr[n].x = el_; erv[n] = er_; }
  }
}

// ---------- kernel 3: fine partition — LDS counting-sort per range into CSR ----------
// 256 blocks, one per range; zero global atomics; writes confined to 150KB/block
__global__ __launch_bounds__(256) void k_part2(
    const int* __restrict__ segcur, const int2* __restrict__ pairs,
    int* __restrict__ csr, int* __restrict__ offs, int* __restrict__ degv)
{
  __shared__ int2 pr[SEGCAP];                     // 32 KB
  __shared__ int cnt[256], sc[256], lcur[256];
  const int t = threadIdx.x;
  const int rb = blockIdx.x;
  const int lo = rb * RW;
  int tot = segcur[rb * CPAD];
  tot = (tot < SEGCAP) ? tot : SEGCAP;
  cnt[t] = 0; lcur[t] = 0;
  __syncthreads();
#pragma unroll
  for (int k = 0; k < SEGCAP / 256; ++k) {
    const int j = k * 256 + t;
    int2 p = make_int2(-1, 0);
    if (j < tot) { p = pairs[rb * SEGCAP + j]; atomicAdd(&cnt[p.x - lo], 1); }
    pr[j] = p;
  }
  __syncthreads();
  // Hillis-Steele inclusive scan -> exclusive base
  const int x = cnt[t];
  sc[t] = x;
  __syncthreads();
  for (int off = 1; off < 256; off <<= 1) {
    const int tmp = (t >= off) ? sc[t - off] : 0;
    __syncthreads();
    sc[t] += tmp;
    __syncthreads();
  }
  const int bs = sc[t] - x;                       // exclusive base for bin t
  const int n = lo + t;
  if (t < RW && n < N_NODES) { offs[n] = rb * SEGCAP + bs; degv[n] = x; }
  sc[t] = bs;                                     // own-slot rewrite (cross-reads only after sync)
  __syncthreads();
#pragma unroll
  for (int k = 0; k < SEGCAP / 256; ++k) {
    const int2 p = pr[k * 256 + t];
    if (p.x >= 0) {
      const int b = p.x - lo;
      const int l = atomicAdd(&lcur[b], 1);
      csr[rb * SEGCAP + sc[b] + l] = p.y;         // ~16 writes/line within one block -> full-line writeback
    }
  }
}

// ---------- kernel 4: single-pass softmax-aggregation + gate + output ----------
// wave per dst node; 12500*4 = 50000 exact
__global__ __launch_bounds__(256) void k_aggregate(
    const int* __restrict__ offs, const int* __restrict__ degv,
    const int* __restrict__ csr,
    const float2* __restrict__ elgr, const float* __restrict__ erv,
    const float* __restrict__ glv, const unsigned int* __restrict__ zg,
    const float* __restrict__ gate_m, float* __restrict__ out)
{
  __shared__ float2 sw[4][64];                    // per-wave (src, ex) stage
  const int wave = threadIdx.x >> 6, lane = threadIdx.x & 63;
  const int n = blockIdx.x * 4 + wave;
  const int deg = degv[n];
  const int base = offs[n];
  const float er_n = erv[n];
  const unsigned int zres_u = zg[n * DIM + lane]; // issue long-latency loads early
  const float gmw = gate_m[lane];
  const float glv_n = glv[n];

  float sum_ex = 0.f, sum_gr = 0.f, hv = 0.f, gm = -INFINITY;

  for (int b = 0; b < deg; b += 64) {
    const int m = (deg - b < 64) ? (deg - b) : 64;

    int s_l = 0; float ex_l = 0.f;
    if (lane < m) {
      s_l = csr[base + b + lane];
      const float2 eg = elgr[s_l];                // 8B gather, 400KB L2-resident
      float ev = eg.x + er_n;
      ev = (ev > 0.f) ? ev : 0.01f * ev;          // leaky_relu slope 0.01
      ex_l = __expf(ev);                          // max-subtract skipped: fp32-safe range
      sum_ex += ex_l;
      sum_gr += eg.y;
    }
    sw[wave][lane] = make_float2(__int_as_float(s_l), ex_l);
    // same-wave LDS ops are in-order

    int j = 0;
    for (; j + 16 <= m; j += 16) {
      float2 q[16];
      unsigned int a[16];
#pragma unroll
      for (int k = 0; k < 16; ++k) q[k] = sw[wave][j + k];
#pragma unroll
      for (int k = 0; k < 16; ++k) a[k] = zg[__float_as_int(q[k].x) * DIM + lane];
#pragma unroll
      for (int k = 0; k < 16; ++k) {
        hv = fmaf(q[k].y, __uint_as_float(a[k] & 0xffff0000u), hv);   // z (bf16 hi)
        gm = fmaxf(gm, __uint_as_float(a[k] << 16));                  // gproj (bf16 lo)
      }
    }
    for (; j + 4 <= m; j += 4) {
      float2 q[4];
      unsigned int a[4];
#pragma unroll
      for (int k = 0; k < 4; ++k) q[k] = sw[wave][j + k];
#pragma unroll
      for (int k = 0; k < 4; ++k) a[k] = zg[__float_as_int(q[k].x) * DIM + lane];
#pragma unroll
      for (int k = 0; k < 4; ++k) {
        hv = fmaf(q[k].y, __uint_as_float(a[k] & 0xffff0000u), hv);
        gm = fmaxf(gm, __uint_as_float(a[k] << 16));
      }
    }
    for (; j < m; ++j) {
      const float2 q = sw[wave][j];
      const unsigned int a = zg[__float_as_int(q.x) * DIM + lane];
      hv = fmaf(q.y, __uint_as_float(a & 0xffff0000u), hv);
      gm = fmaxf(gm, __uint_as_float(a << 16));
    }
  }

  sum_ex = wave_reduce_sum(sum_ex);
  sum_gr = wave_reduce_sum(sum_gr);
  const float inv = (deg > 0) ? 1.f / sum_ex : 0.f;   // guard 0*inf NaN
  hv *= inv;

  const float gmv = (deg > 0) ? gm : 0.f;
  const float dot = wave_reduce_sum(gmv * gmw);
  const float x = glv_n + dot + sum_gr / fmaxf((float)deg, 1.f);
  const float gval = 1.f / (1.f + expf(-x));
  const float zres = __uint_as_float(zres_u & 0xffff0000u);
  out[n * DIM + lane] = zres + gval * hv;
}

// ---------- launch ----------
extern "C" void kernel_launch(void* const* d_in, const int* in_sizes, int n_in,
                              void* d_out, int out_size, void* d_ws, size_t ws_size,
                              hipStream_t stream) {
  const float* v      = (const float*)d_in[0];
  const int*   src    = (const int*)d_in[1];
  const int*   dst    = (const int*)d_in[2];
  const float* Wa     = (const float*)d_in[3];
  const float* att_l  = (const float*)d_in[4];
  const float* att_r  = (const float*)d_in[5];
  const float* gate_l = (const float*)d_in[6];
  const float* gate_m = (const float*)d_in[7];
  const float* gate_r = (const float*)d_in[8];
  const float* Wgm    = (const float*)d_in[9];
  float* out = (float*)d_out;

  // workspace layout (~26.5 MB)
  int2* pairs  = (int2*)d_ws;                      // NR*SEGCAP int2 (8 MB, 8B-aligned)
  unsigned int* zg = (unsigned int*)(pairs + NR * SEGCAP);   // N*64 u32 (12.8 MB)
  float2* elgr = (float2*)(zg + N_NODES * DIM);    // N float2 (0.4 MB)
  float* erv   = (float*)(elgr + N_NODES);         // N
  float* glv   = erv + N_NODES;                    // N
  int* csr     = (int*)(glv + N_NODES);            // NR*SEGCAP (4 MB)
  int* offs    = csr + NR * SEGCAP;                // N
  int* degv    = offs + N_NODES;                   // N
  int* segcur  = degv + N_NODES;                   // NR*CPAD (16 KB)

  hipMemsetAsync(segcur, 0, NR * CPAD * sizeof(int), stream);

  k_part1<<<NB1, 256, 0, stream>>>(src, dst, segcur, pairs);
  k_proj<<<3125, 256, 0, stream>>>(v, Wa, att_l, att_r, gate_l, gate_r, Wgm,
                                   zg, elgr, erv, glv);
  k_part2<<<NR, 256, 0, stream>>>(segcur, pairs, csr, offs, degv);
  k_aggregate<<<12500, 256, 0, stream>>>(offs, degv, csr, elgr, erv, glv, zg, gate_m, out);
}